// Round 5
// baseline (735.360 us; speedup 1.0000x reference)
//
#include <hip/hip_runtime.h>

// ActorCritic fused: LSTM scan (B=1024,T=256,F=128,H=128) + MLP heads.
// R5: producer rebuilt (8-t batching, 256-VGPR cap -> no spill, 8 loads in
//     flight per thread); scan spread to 128 blocks x 8 rows (halves per-SIMD
//     VALU issue) with 2-step-deep xg prefetch.
// Fallback to R3 monolithic kernel when ws_size < 256 MiB.

typedef _Float16 f16x8 __attribute__((ext_vector_type(8)));
typedef _Float16 f16x4 __attribute__((ext_vector_type(4)));
typedef float    f32x4 __attribute__((ext_vector_type(4)));

#define NLOG2E (-1.4426950408889634f)

__device__ __forceinline__ float rcpf(float x) { return __builtin_amdgcn_rcpf(x); }
__device__ __forceinline__ float ex2(float x)  { return __builtin_amdgcn_exp2f(x); }
__device__ __forceinline__ float dpp_swap1(float x) {
    return __builtin_bit_cast(float,
        __builtin_amdgcn_mov_dpp(__builtin_bit_cast(int, x), 0xB1, 0xF, 0xF, true));
}

// ============================ kernel 1: xg GEMM ============================
// grid 512: blk = b&63 -> 16 batch rows; tq = b>>6 -> 32 t's. 8 t's per barrier.
__global__ __launch_bounds__(512, 1)
void xg_gemm8(const float* __restrict__ hin, const float* __restrict__ Wx,
              _Float16* __restrict__ xg)
{
    __shared__ f16x8 As[8][256];            // 32 KB
    const int tid  = threadIdx.x;
    const int lane = tid & 63;
    const int wv   = tid >> 6;
    const int m16  = lane & 15;
    const int q    = lane >> 4;
    const int blk  = blockIdx.x & 63;
    const int tq   = blockIdx.x >> 6;       // 0..7
    const int r0   = blk << 4;
    const int ncol = (wv << 4) + m16;

    f16x8 bwx[4][4];
    #pragma unroll
    for (int kt = 0; kt < 4; ++kt)
        #pragma unroll
        for (int s = 0; s < 4; ++s) {
            f16x8 v;
            #pragma unroll
            for (int j = 0; j < 8; ++j) {
                const int k = (kt << 5) + (q << 3) + j;       // 0..127
                v[j] = (_Float16)Wx[k * 512 + s * 128 + ncol];
            }
            bwx[s][kt] = v;
        }

    const int xc  = tid >> 1, xh = tid & 1;
    const int xm  = xc & 15;
    const int xk0 = ((xc >> 6) << 5) + (((xc >> 4) & 3) << 3) + (xh << 2);
    const float* pxb = hin + (size_t)(r0 + xm) * 256 * 128 + xk0;

    for (int grp = 0; grp < 4; ++grp) {
        const int t0 = (tq << 5) + (grp << 3);
        // 8 staging loads in flight per thread
        float4 xr[8];
        #pragma unroll
        for (int i = 0; i < 8; ++i)
            xr[i] = *(const float4*)(pxb + (size_t)(t0 + i) * 128);
        #pragma unroll
        for (int i = 0; i < 8; ++i) {
            f16x4 pk;
            pk[0] = (_Float16)xr[i].x; pk[1] = (_Float16)xr[i].y;
            pk[2] = (_Float16)xr[i].z; pk[3] = (_Float16)xr[i].w;
            *(f16x4*)((_Float16*)&As[i][0] + xc * 8 + xh * 4) = pk;
        }
        __syncthreads();
        #pragma unroll
        for (int i = 0; i < 8; ++i) {
            f16x8 af[4];
            #pragma unroll
            for (int kt = 0; kt < 4; ++kt) af[kt] = As[i][(kt << 6) + lane];
            _Float16* outp = xg + (((size_t)(t0 + i) * 64 + blk) * 8 + wv) * 1024 + lane * 4;
            #pragma unroll
            for (int s = 0; s < 4; ++s) {
                f32x4 z = {0.f, 0.f, 0.f, 0.f};
                #pragma unroll
                for (int kt = 0; kt < 4; ++kt)
                    z = __builtin_amdgcn_mfma_f32_16x16x32_f16(af[kt], bwx[s][kt], z, 0, 0, 0);
                f16x4 o;
                o[0] = (_Float16)z[0]; o[1] = (_Float16)z[1];
                o[2] = (_Float16)z[2]; o[3] = (_Float16)z[3];
                *(f16x4*)(outp + s * 256) = o;
            }
        }
        __syncthreads();
    }
}

// ============================ kernel 2: scan ===============================
// 128 blocks x 8 batch rows (M=8 inside the 16-row MFMA tile; rows 8..15 zero).
__global__ __launch_bounds__(512, 2)
void ac_scan8(const _Float16* __restrict__ xg,
              const float* __restrict__ Wh, const float* __restrict__ bh,
              const float* __restrict__ Wa1, const float* __restrict__ ba1,
              const float* __restrict__ Wa2, const float* __restrict__ ba2,
              const float* __restrict__ Wa3, const float* __restrict__ ba3,
              const float* __restrict__ logstd,
              const float* __restrict__ Wc1, const float* __restrict__ bc1,
              const float* __restrict__ Wc2, const float* __restrict__ bc2,
              const float* __restrict__ Wc3, const float* __restrict__ bc3,
              float* __restrict__ out)
{
    constexpr int T = 256;

    __shared__ f16x8 Abuf[2][256];          // 8 KB
    __shared__ float xf[8][129];
    __shared__ float hb[2][8][257];

    const int tid  = threadIdx.x;
    const int lane = tid & 63;
    const int wv   = tid >> 6;
    const int m16  = lane & 15;
    const int q    = lane >> 4;
    const int blk  = blockIdx.x;            // 0..127
    const int pb   = blk & 1;               // which half of producer's 16-row tile
    const int blkp = blk >> 1;              // producer block
    const int r0   = blk << 3;              // 8 rows
    const int ncol = (wv << 4) + m16;

    // Wh B-fragments (K=128): 64 VGPRs
    f16x8 bwh[4][4];
    #pragma unroll
    for (int kt = 0; kt < 4; ++kt)
        #pragma unroll
        for (int s = 0; s < 4; ++s) {
            f16x8 v;
            #pragma unroll
            for (int j = 0; j < 8; ++j) {
                const int k = (kt << 5) + (q << 3) + j;       // 0..127
                v[j] = (_Float16)Wh[k * 512 + s * 128 + ncol];
            }
            bwh[s][kt] = v;
        }
    const float nbi = NLOG2E * bh[0 * 128 + ncol];
    const float nbf = NLOG2E * bh[1 * 128 + ncol];
    const float nbg = 2.0f * NLOG2E * bh[2 * 128 + ncol];
    const float nbo = NLOG2E * bh[3 * 128 + ncol];

    // h-write target (rows 0..7 only, held by q<2 lanes)
    const int hch = ((ncol >> 5) << 6) + (((ncol >> 3) & 3) << 4);
    _Float16* hw0 = (_Float16*)&Abuf[0][0] + (hch + (q << 2)) * 8 + (ncol & 7);
    _Float16* hw1 = (_Float16*)&Abuf[1][0] + (hch + (q << 2)) * 8 + (ncol & 7);

    // zero BOTH buffers (rows 8..15 must stay zero forever)
    ((f16x4*)&Abuf[0][0])[tid]       = f16x4{};
    ((f16x4*)&Abuf[0][0])[tid + 512] = f16x4{};

    // xg fragment pointer: row r (0..7) of this block = producer row pb*8+r,
    // i.e. producer lane quad q_p = q + 2*pb.
    const int xl = m16 | (((q + (pb << 1)) & 3) << 4);
    const uint2* xp = (const uint2*)xg + ((size_t)blkp * 8 + wv) * 256 + xl;
    const size_t XS = 131072;               // uint2 per t

    uint2 c0 = xp[0], c1 = xp[64], c2 = xp[128], c3 = xp[192]; xp += XS;
    uint2 n0 = xp[0], n1 = xp[64], n2 = xp[128], n3 = xp[192]; xp += XS;

    f32x4 cst = {0.f, 0.f, 0.f, 0.f};
    f32x4 hlast;

    __syncthreads();

    for (int t = 0; t < T; ++t) {
        // issue load for t+2 (2-step-deep prefetch covers HBM latency)
        uint2 f0 = n0, f1 = n1, f2 = n2, f3 = n3;
        if (t + 2 < T) {
            f0 = xp[0]; f1 = xp[64]; f2 = xp[128]; f3 = xp[192];
            xp += XS;
        }

        // z init = xg fragment (f16 -> f32)
        const f16x4 v0 = __builtin_bit_cast(f16x4, c0);
        const f16x4 v1 = __builtin_bit_cast(f16x4, c1);
        const f16x4 v2 = __builtin_bit_cast(f16x4, c2);
        const f16x4 v3 = __builtin_bit_cast(f16x4, c3);
        f32x4 z0 = {(float)v0[0], (float)v0[1], (float)v0[2], (float)v0[3]};
        f32x4 z1 = {(float)v1[0], (float)v1[1], (float)v1[2], (float)v1[3]};
        f32x4 z2 = {(float)v2[0], (float)v2[1], (float)v2[2], (float)v2[3]};
        f32x4 z3 = {(float)v3[0], (float)v3[1], (float)v3[2], (float)v3[3]};

        // MFMA: z += h @ Wh (K=128)
        const f16x8* Ab = &Abuf[t & 1][0];
        f16x8 af[4];
        #pragma unroll
        for (int kt = 0; kt < 4; ++kt) af[kt] = Ab[(kt << 6) + lane];
        #pragma unroll
        for (int kt = 0; kt < 4; ++kt) {
            z0 = __builtin_amdgcn_mfma_f32_16x16x32_f16(af[kt], bwh[0][kt], z0, 0, 0, 0);
            z1 = __builtin_amdgcn_mfma_f32_16x16x32_f16(af[kt], bwh[1][kt], z1, 0, 0, 0);
            z2 = __builtin_amdgcn_mfma_f32_16x16x32_f16(af[kt], bwh[2][kt], z2, 0, 0, 0);
            z3 = __builtin_amdgcn_mfma_f32_16x16x32_f16(af[kt], bwh[3][kt], z3, 0, 0, 0);
        }

        // cell update (rows q*4+g valid only for q<2; others compute garbage,
        // never written)
        _Float16* hw = (t & 1) ? hw0 : hw1;   // points into NEXT buffer
        #pragma unroll
        for (int g = 0; g < 4; ++g) {
            const float iv = rcpf(1.0f + ex2(fmaf(z0[g], NLOG2E, nbi)));
            const float fv = rcpf(1.0f + ex2(fmaf(z1[g], NLOG2E, nbf)));
            const float gv = 2.0f * rcpf(1.0f + ex2(fmaf(z2[g], 2.0f * NLOG2E, nbg))) - 1.0f;
            const float ov = rcpf(1.0f + ex2(fmaf(z3[g], NLOG2E, nbo)));
            const float cn = fv * cst[g] + iv * gv;
            cst[g] = cn;
            const float th = 2.0f * rcpf(1.0f + ex2(cn * (2.0f * NLOG2E))) - 1.0f;
            hlast[g] = ov * th;
        }
        if (q < 2) {
            #pragma unroll
            for (int g = 0; g < 4; ++g) hw[g * 8] = (_Float16)hlast[g];
        }

        c0 = n0; c1 = n1; c2 = n2; c3 = n3;
        n0 = f0; n1 = f1; n2 = f2; n3 = f3;
        __syncthreads();
    }

    // final hidden (rows 0..7) to LDS for heads
    if (q < 2) {
        #pragma unroll
        for (int g = 0; g < 4; ++g) xf[(q << 2) + g][ncol] = hlast[g];
    }
    __syncthreads();

    // ---- MLP heads (8 rows) ----
    const int n  = tid & 255;
    const int rh = tid >> 8;                 // 0..1 -> rows rh*4..rh*4+3
    auto tanhl = [&](float x) { return 2.0f * rcpf(1.0f + ex2(x * (2.0f * NLOG2E))) - 1.0f; };

    auto layer = [&](const float* __restrict__ W, const float* __restrict__ bv,
                     const float* xin, int xs, int K, float* yout, int ys) {
        float acc[4];
        const float b = bv[n];
        #pragma unroll
        for (int r = 0; r < 4; ++r) acc[r] = b;
        #pragma unroll 4
        for (int k = 0; k < K; ++k) {
            const float w = W[k * 256 + n];
            #pragma unroll
            for (int r = 0; r < 4; ++r) acc[r] += xin[(rh * 4 + r) * xs + k] * w;
        }
        #pragma unroll
        for (int r = 0; r < 4; ++r) yout[(rh * 4 + r) * ys + n] = tanhl(acc[r]);
    };

    layer(Wa1, ba1, &xf[0][0], 129, 128, &hb[0][0][0], 257);
    __syncthreads();
    layer(Wa2, ba2, &hb[0][0][0], 257, 256, &hb[1][0][0], 257);
    __syncthreads();
    layer(Wc1, bc1, &xf[0][0], 129, 128, &hb[0][0][0], 257);
    if (tid < 64) {                          // actor L3: 8 rows x 8 actions
        const int r = tid >> 3, aa = tid & 7;
        float acc = ba3[aa];
        #pragma unroll 4
        for (int k = 0; k < 256; ++k) acc += hb[1][r][k] * Wa3[k * 8 + aa];
        out[(size_t)(r0 + r) * 17 + aa]     = acc;
        out[(size_t)(r0 + r) * 17 + 8 + aa] = __expf(logstd[aa]);
    }
    __syncthreads();
    layer(Wc2, bc2, &hb[0][0][0], 257, 256, &hb[1][0][0], 257);
    __syncthreads();
    if (tid < 8) {                           // critic L3
        const int r = tid;
        float acc = bc3[0];
        #pragma unroll 4
        for (int k = 0; k < 256; ++k) acc += hb[1][r][k] * Wc3[k];
        out[(size_t)(r0 + r) * 17 + 16] = acc;
    }
}

// ==================== fallback: R3 monolithic kernel =======================
__global__ __launch_bounds__(512, 2)
void ac_fused(const float* __restrict__ hin,
              const float* __restrict__ Wx, const float* __restrict__ Wh,
              const float* __restrict__ bh,
              const float* __restrict__ Wa1, const float* __restrict__ ba1,
              const float* __restrict__ Wa2, const float* __restrict__ ba2,
              const float* __restrict__ Wa3, const float* __restrict__ ba3,
              const float* __restrict__ logstd,
              const float* __restrict__ Wc1, const float* __restrict__ bc1,
              const float* __restrict__ Wc2, const float* __restrict__ bc2,
              const float* __restrict__ Wc3, const float* __restrict__ bc3,
              float* __restrict__ out)
{
    constexpr int T = 256, F = 128, H = 128, G = 512;

    __shared__ f16x8 Abuf[2][512];
    __shared__ float xf[16][F + 1];
    __shared__ float hb[2][16][257];

    const int tid  = threadIdx.x;
    const int lane = tid & 63;
    const int wv   = tid >> 6;
    const int m16  = lane & 15;
    const int q    = lane >> 4;
    const int p    = lane & 1;
    const int r0   = blockIdx.x << 4;

    f16x8 bw[4][8];
    const int ncol = (wv << 4) + m16;
    #pragma unroll
    for (int kt = 0; kt < 8; ++kt) {
        #pragma unroll
        for (int s = 0; s < 4; ++s) {
            f16x8 v;
            #pragma unroll
            for (int j = 0; j < 8; ++j) {
                const int k = (kt << 5) + (q << 3) + j;
                const float w = (k < F) ? Wx[k * G + s * H + ncol]
                                        : Wh[(k - F) * G + s * H + ncol];
                v[j] = (_Float16)w;
            }
            bw[s][kt] = v;
        }
    }
    const float nbi = NLOG2E * bh[0 * H + ncol];
    const float nbf = NLOG2E * bh[1 * H + ncol];
    const float nbg = 2.0f * NLOG2E * bh[2 * H + ncol];
    const float nbo = NLOG2E * bh[3 * H + ncol];

    const int xc = tid >> 1;
    const int xh = tid & 1;
    const int xm = xc & 15;
    const int xk0 = ((xc >> 6) << 5) + (((xc >> 4) & 3) << 3) + (xh << 2);
    const float* pxbase = hin + (size_t)(r0 + xm) * T * F + xk0;

    const int dimc = (wv << 4) + m16;
    const int kk   = F + dimc;
    const int hchunk = ((kk >> 5) << 6) + (((kk >> 3) & 3) << 4);
    const int a    = (m16 & 7) >> 1;
    const int widx0 = (hchunk + (q << 2) + (p << 1)) * 4 + a;
    const int widx1 = widx0 + 4;

    {
        const float4 x0 = *(const float4*)pxbase;
        f16x4 pk;
        pk[0] = (_Float16)x0.x; pk[1] = (_Float16)x0.y;
        pk[2] = (_Float16)x0.z; pk[3] = (_Float16)x0.w;
        *(f16x4*)((_Float16*)&Abuf[0][0] + xc * 8 + xh * 4) = pk;
        f16x4 zz = {};
        *(f16x4*)((_Float16*)&Abuf[0][0] + (256 + xc) * 8 + xh * 4) = zz;
    }

    f32x4 cst = {0.f, 0.f, 0.f, 0.f};
    f32x4 hlast;

    __syncthreads();

    for (int t = 0; t < T; ++t) {
        const int tp = (t + 1 < T) ? t + 1 : T - 1;
        const float4 xn = *(const float4*)(pxbase + (size_t)tp * F);

        const f16x8* Ab = &Abuf[t & 1][0];
        f32x4 z0 = {0.f, 0.f, 0.f, 0.f};
        f32x4 z1 = {0.f, 0.f, 0.f, 0.f};
        f32x4 z2 = {0.f, 0.f, 0.f, 0.f};
        f32x4 z3 = {0.f, 0.f, 0.f, 0.f};
        #pragma unroll
        for (int kt = 0; kt < 8; ++kt) {
            const f16x8 af = Ab[(kt << 6) + lane];
            z0 = __builtin_amdgcn_mfma_f32_16x16x32_f16(af, bw[0][kt], z0, 0, 0, 0);
            z1 = __builtin_amdgcn_mfma_f32_16x16x32_f16(af, bw[1][kt], z1, 0, 0, 0);
            z2 = __builtin_amdgcn_mfma_f32_16x16x32_f16(af, bw[2][kt], z2, 0, 0, 0);
            z3 = __builtin_amdgcn_mfma_f32_16x16x32_f16(af, bw[3][kt], z3, 0, 0, 0);
        }

        #pragma unroll
        for (int g = 0; g < 4; ++g) {
            const float iv = rcpf(1.0f + ex2(fmaf(z0[g], NLOG2E, nbi)));
            const float fv = rcpf(1.0f + ex2(fmaf(z1[g], NLOG2E, nbf)));
            const float gv = 2.0f * rcpf(1.0f + ex2(fmaf(z2[g], 2.0f * NLOG2E, nbg))) - 1.0f;
            const float ov = rcpf(1.0f + ex2(fmaf(z3[g], NLOG2E, nbo)));
            const float cn = fv * cst[g] + iv * gv;
            cst[g] = cn;
            const float th = 2.0f * rcpf(1.0f + ex2(cn * (2.0f * NLOG2E))) - 1.0f;
            hlast[g] = ov * th;
        }

        uint32_t* An32 = (uint32_t*)&Abuf[(t + 1) & 1][0];
        uint32_t dd[4];
        #pragma unroll
        for (int g = 0; g < 4; ++g) {
            const float pp = dpp_swap1(hlast[g]);
            const float lo = p ? pp : hlast[g];
            const float hi = p ? hlast[g] : pp;
            dd[g] = __builtin_bit_cast(uint32_t, __builtin_amdgcn_cvt_pkrtz(lo, hi));
        }
        An32[widx0] = p ? dd[2] : dd[0];
        An32[widx1] = p ? dd[3] : dd[1];

        {
            f16x4 pk;
            pk[0] = (_Float16)xn.x; pk[1] = (_Float16)xn.y;
            pk[2] = (_Float16)xn.z; pk[3] = (_Float16)xn.w;
            *(f16x4*)((_Float16*)An32 + xc * 8 + xh * 4) = pk;
        }
        __syncthreads();
    }

    #pragma unroll
    for (int g = 0; g < 4; ++g) xf[(q << 2) + g][dimc] = hlast[g];
    __syncthreads();

    const int n  = tid & 255;
    const int rh = tid >> 8;
    auto tanhl = [&](float x) { return 2.0f * rcpf(1.0f + ex2(x * (2.0f * NLOG2E))) - 1.0f; };

    auto layer = [&](const float* __restrict__ W, const float* __restrict__ bv,
                     const float* xin, int xs, int K, float* yout, int ys) {
        float acc[8];
        const float b = bv[n];
        #pragma unroll
        for (int r = 0; r < 8; ++r) acc[r] = b;
        #pragma unroll 4
        for (int k = 0; k < K; ++k) {
            const float w = W[k * 256 + n];
            #pragma unroll
            for (int r = 0; r < 8; ++r) acc[r] += xin[(rh * 8 + r) * xs + k] * w;
        }
        #pragma unroll
        for (int r = 0; r < 8; ++r) yout[(rh * 8 + r) * ys + n] = tanhl(acc[r]);
    };

    layer(Wa1, ba1, &xf[0][0], F + 1, 128, &hb[0][0][0], 257);
    __syncthreads();
    layer(Wa2, ba2, &hb[0][0][0], 257, 256, &hb[1][0][0], 257);
    __syncthreads();
    layer(Wc1, bc1, &xf[0][0], F + 1, 128, &hb[0][0][0], 257);
    if (tid < 128) {
        const int r = tid >> 3, aa = tid & 7;
        float acc = ba3[aa];
        #pragma unroll 4
        for (int k = 0; k < 256; ++k) acc += hb[1][r][k] * Wa3[k * 8 + aa];
        out[(size_t)(r0 + r) * 17 + aa]     = acc;
        out[(size_t)(r0 + r) * 17 + 8 + aa] = __expf(logstd[aa]);
    }
    __syncthreads();
    layer(Wc2, bc2, &hb[0][0][0], 257, 256, &hb[1][0][0], 257);
    __syncthreads();
    if (tid < 16) {
        const int r = tid;
        float acc = bc3[0];
        #pragma unroll 4
        for (int k = 0; k < 256; ++k) acc += hb[1][r][k] * Wc3[k];
        out[(size_t)(r0 + r) * 17 + 16] = acc;
    }
}

extern "C" void kernel_launch(void* const* d_in, const int* in_sizes, int n_in,
                              void* d_out, int out_size, void* d_ws, size_t ws_size,
                              hipStream_t stream) {
    (void)in_sizes; (void)n_in; (void)out_size;
    const float* hin = (const float*)d_in[0];
    const float* Wx  = (const float*)d_in[1];
    const float* Wh  = (const float*)d_in[2];
    const float* bh  = (const float*)d_in[3];
    const float* Wa1 = (const float*)d_in[4];
    const float* ba1 = (const float*)d_in[5];
    const float* Wa2 = (const float*)d_in[6];
    const float* ba2 = (const float*)d_in[7];
    const float* Wa3 = (const float*)d_in[8];
    const float* ba3 = (const float*)d_in[9];
    const float* ls  = (const float*)d_in[10];
    const float* Wc1 = (const float*)d_in[11];
    const float* bc1 = (const float*)d_in[12];
    const float* Wc2 = (const float*)d_in[13];
    const float* bc2 = (const float*)d_in[14];
    const float* Wc3 = (const float*)d_in[15];
    const float* bc3 = (const float*)d_in[16];

    const size_t XG_BYTES = (size_t)256 * 1024 * 1024;  // B*T*4H f16
    if (ws_size >= XG_BYTES) {
        _Float16* xg = (_Float16*)d_ws;
        hipLaunchKernelGGL(xg_gemm8, dim3(512), dim3(512), 0, stream, hin, Wx, xg);
        hipLaunchKernelGGL(ac_scan8, dim3(128), dim3(512), 0, stream,
                           xg, Wh, bh, Wa1, ba1, Wa2, ba2, Wa3, ba3, ls,
                           Wc1, bc1, Wc2, bc2, Wc3, bc3, (float*)d_out);
    } else {
        hipLaunchKernelGGL(ac_fused, dim3(64), dim3(512), 0, stream,
                           hin, Wx, Wh, bh, Wa1, ba1, Wa2, ba2, Wa3, ba3, ls,
                           Wc1, bc1, Wc2, bc2, Wc3, bc3, (float*)d_out);
    }
}

// Round 6
// 613.007 us; speedup vs baseline: 1.1996x; 1.1996x over previous
//
#include <hip/hip_runtime.h>

// ActorCritic fused kernel: LSTM scan (B=1024,T=256,F=128,H=128) + MLP heads.
// 64 blocks x 512 threads; block owns 16 batch rows; weights resident in VGPRs
// as fp16 MFMA B-fragments; A operand ([x_t | h_t], K=256) double-buffered in
// LDS in fragment order.
// R6: fused architecture (split regressed: producer ~115us + 500MB extra HBM);
//     direct b16 h-writes (no DPP pack), x-store before acts, pkrtz staging,
//     t-loop unrolled x2 for static buffer selection.

typedef _Float16 f16x8 __attribute__((ext_vector_type(8)));
typedef _Float16 f16x4 __attribute__((ext_vector_type(4)));
typedef float    f32x4 __attribute__((ext_vector_type(4)));

#define NLOG2E (-1.4426950408889634f)

__device__ __forceinline__ float rcpf(float x) { return __builtin_amdgcn_rcpf(x); }
__device__ __forceinline__ float ex2(float x)  { return __builtin_amdgcn_exp2f(x); }

__global__ __launch_bounds__(512, 2)
void ac_fused(const float* __restrict__ hin,
              const float* __restrict__ Wx, const float* __restrict__ Wh,
              const float* __restrict__ bh,
              const float* __restrict__ Wa1, const float* __restrict__ ba1,
              const float* __restrict__ Wa2, const float* __restrict__ ba2,
              const float* __restrict__ Wa3, const float* __restrict__ ba3,
              const float* __restrict__ logstd,
              const float* __restrict__ Wc1, const float* __restrict__ bc1,
              const float* __restrict__ Wc2, const float* __restrict__ bc2,
              const float* __restrict__ Wc3, const float* __restrict__ bc3,
              float* __restrict__ out)
{
    constexpr int T = 256, F = 128, H = 128, G = 512; // G = 4*H

    // A staging in MFMA fragment order: chunk = kt*64 + quad*16 + m holds
    // A[m][k], k = kt*32 + quad*8 + j (j = index inside the f16x8 chunk).
    __shared__ f16x8 Abuf[2][512];          // 2 x 8 KB
    __shared__ float xf[16][F + 1];         // final hidden (fp32)
    __shared__ float hb[2][16][257];        // head layer ping-pong

    const int tid  = threadIdx.x;
    const int lane = tid & 63;
    const int wv   = tid >> 6;    // wave 0..7
    const int m16  = lane & 15;
    const int q    = lane >> 4;   // quad 0..3
    const int r0   = blockIdx.x << 4;

    // ---- weight B-fragments in registers ----
    // wave wv covers column (s*128 + wv*16 + m16) in each gate section s
    f16x8 bw[4][8];
    const int ncol = (wv << 4) + m16;
    #pragma unroll
    for (int kt = 0; kt < 8; ++kt) {
        #pragma unroll
        for (int s = 0; s < 4; ++s) {
            f16x8 v;
            #pragma unroll
            for (int j = 0; j < 8; ++j) {
                const int k = (kt << 5) + (q << 3) + j;   // 0..255
                const float w = (k < F) ? Wx[k * G + s * H + ncol]
                                        : Wh[(k - F) * G + s * H + ncol];
                v[j] = (_Float16)w;
            }
            bw[s][kt] = v;
        }
    }
    // bias folded into the exp2 argument: sig(z+b) = rcp(1 + 2^(z*NLOG2E + nb))
    const float nbi = NLOG2E * bh[0 * H + ncol];
    const float nbf = NLOG2E * bh[1 * H + ncol];
    const float nbg = 2.0f * NLOG2E * bh[2 * H + ncol];
    const float nbo = NLOG2E * bh[3 * H + ncol];

    // ---- x staging mapping: thread stages half-chunk (chunk tid>>1, half tid&1)
    const int xc  = tid >> 1;
    const int xh  = tid & 1;
    const int xm  = xc & 15;
    const int xk0 = ((xc >> 6) << 5) + (((xc >> 4) & 3) << 3) + (xh << 2);
    const float* pxbase = hin + (size_t)(r0 + xm) * T * F + xk0;

    // ---- h-write targets (direct b16; 4 rows q*4+g at k = 128+ncol) ----
    const int kk  = F + ncol;
    const int hch = ((kk >> 5) << 6) + (((kk >> 3) & 3) << 4);
    _Float16* const hwp0 = (_Float16*)&Abuf[0][0] + (hch + (q << 2)) * 8 + (kk & 7);
    _Float16* const hwp1 = (_Float16*)&Abuf[1][0] + (hch + (q << 2)) * 8 + (kk & 7);

    // ---- stage x_0 and h_0 = 0 into Abuf[0] ----
    {
        const float4 x0 = *(const float4*)pxbase;
        auto p01 = __builtin_amdgcn_cvt_pkrtz(x0.x, x0.y);
        auto p23 = __builtin_amdgcn_cvt_pkrtz(x0.z, x0.w);
        f16x4 pk; pk[0] = p01[0]; pk[1] = p01[1]; pk[2] = p23[0]; pk[3] = p23[1];
        *(f16x4*)((_Float16*)&Abuf[0][0] + xc * 8 + xh * 4) = pk;
        f16x4 zz = {};
        *(f16x4*)((_Float16*)&Abuf[0][0] + (256 + xc) * 8 + xh * 4) = zz;
    }

    f32x4 cst = {0.f, 0.f, 0.f, 0.f};   // cell state: rows q*4+g, dim ncol
    f32x4 hlast;

    __syncthreads();

    // one LSTM step: read Abuf[rb], write Abuf[rb^1]; rb is compile-time-ish
    auto step = [&](int rb, int t) {
        // prefetch x_{t+1} (latency hidden under MFMA)
        const int tp = (t + 1 < T) ? t + 1 : T - 1;
        const float4 xn = *(const float4*)(pxbase + (size_t)tp * F);

        // MFMA: z = [x_t, h_t] @ W  (bias folded into activations)
        const f16x8* Ab = &Abuf[rb][0];
        f16x8 af[8];
        #pragma unroll
        for (int kt = 0; kt < 8; ++kt) af[kt] = Ab[(kt << 6) + lane];
        f32x4 z0 = {0.f, 0.f, 0.f, 0.f};
        f32x4 z1 = {0.f, 0.f, 0.f, 0.f};
        f32x4 z2 = {0.f, 0.f, 0.f, 0.f};
        f32x4 z3 = {0.f, 0.f, 0.f, 0.f};
        #pragma unroll
        for (int kt = 0; kt < 8; ++kt) {
            z0 = __builtin_amdgcn_mfma_f32_16x16x32_f16(af[kt], bw[0][kt], z0, 0, 0, 0);
            z1 = __builtin_amdgcn_mfma_f32_16x16x32_f16(af[kt], bw[1][kt], z1, 0, 0, 0);
            z2 = __builtin_amdgcn_mfma_f32_16x16x32_f16(af[kt], bw[2][kt], z2, 0, 0, 0);
            z3 = __builtin_amdgcn_mfma_f32_16x16x32_f16(af[kt], bw[3][kt], z3, 0, 0, 0);
        }

        // store prefetched x_{t+1} into the next buffer NOW — its vmcnt wait and
        // LDS write overlap the activation latency below
        _Float16* const An = (_Float16*)&Abuf[rb ^ 1][0];
        {
            auto p01 = __builtin_amdgcn_cvt_pkrtz(xn.x, xn.y);
            auto p23 = __builtin_amdgcn_cvt_pkrtz(xn.z, xn.w);
            f16x4 pk; pk[0] = p01[0]; pk[1] = p01[1]; pk[2] = p23[0]; pk[3] = p23[1];
            *(f16x4*)(An + xc * 8 + xh * 4) = pk;
        }

        // cell update (4 cells/lane, all gates lane-local) + direct b16 h-write
        _Float16* const hw = rb ? hwp0 : hwp1;   // write into buffer rb^1
        #pragma unroll
        for (int g = 0; g < 4; ++g) {
            const float iv = rcpf(1.0f + ex2(fmaf(z0[g], NLOG2E, nbi)));
            const float fv = rcpf(1.0f + ex2(fmaf(z1[g], NLOG2E, nbf)));
            const float gv = 2.0f * rcpf(1.0f + ex2(fmaf(z2[g], 2.0f * NLOG2E, nbg))) - 1.0f;
            const float ov = rcpf(1.0f + ex2(fmaf(z3[g], NLOG2E, nbo)));
            const float cn = fv * cst[g] + iv * gv;
            cst[g] = cn;
            const float th = 2.0f * rcpf(1.0f + ex2(cn * (2.0f * NLOG2E))) - 1.0f;
            hlast[g] = ov * th;
            hw[g * 8] = (_Float16)hlast[g];      // ds_write_b16
        }
        __syncthreads();
    };

    #pragma unroll 1
    for (int t2 = 0; t2 < T / 2; ++t2) {
        step(0, t2 * 2);       // buf0 -> buf1
        step(1, t2 * 2 + 1);   // buf1 -> buf0
    }

    // ---- final hidden (fp32, pre-rounding) to LDS for the heads ----
    #pragma unroll
    for (int g = 0; g < 4; ++g) xf[(q << 2) + g][ncol] = hlast[g];
    __syncthreads();

    // ---- MLP heads (fp32 VALU; tiny FLOPs) ----
    const int n  = tid & 255;
    const int rh = tid >> 8;
    auto tanhl = [&](float x) { return 2.0f * rcpf(1.0f + ex2(x * (2.0f * NLOG2E))) - 1.0f; };

    auto layer = [&](const float* __restrict__ W, const float* __restrict__ bv,
                     const float* xin, int xs, int K, float* yout, int ys) {
        float acc[8];
        const float b = bv[n];
        #pragma unroll
        for (int r = 0; r < 8; ++r) acc[r] = b;
        #pragma unroll 4
        for (int k = 0; k < K; ++k) {
            const float w = W[k * 256 + n];
            #pragma unroll
            for (int r = 0; r < 8; ++r) acc[r] += xin[(rh * 8 + r) * xs + k] * w;
        }
        #pragma unroll
        for (int r = 0; r < 8; ++r) yout[(rh * 8 + r) * ys + n] = tanhl(acc[r]);
    };

    layer(Wa1, ba1, &xf[0][0], F + 1, 128, &hb[0][0][0], 257);   // actor L1
    __syncthreads();
    layer(Wa2, ba2, &hb[0][0][0], 257, 256, &hb[1][0][0], 257);  // actor L2
    __syncthreads();
    layer(Wc1, bc1, &xf[0][0], F + 1, 128, &hb[0][0][0], 257);   // critic L1
    if (tid < 128) {                                             // actor L3: mean + std
        const int r = tid >> 3, aa = tid & 7;
        float acc = ba3[aa];
        #pragma unroll 4
        for (int k = 0; k < 256; ++k) acc += hb[1][r][k] * Wa3[k * 8 + aa];
        out[(size_t)(r0 + r) * 17 + aa]     = acc;
        out[(size_t)(r0 + r) * 17 + 8 + aa] = __expf(logstd[aa]);
    }
    __syncthreads();
    layer(Wc2, bc2, &hb[0][0][0], 257, 256, &hb[1][0][0], 257);  // critic L2
    __syncthreads();
    if (tid < 16) {                                              // critic L3: value
        const int r = tid;
        float acc = bc3[0];
        #pragma unroll 4
        for (int k = 0; k < 256; ++k) acc += hb[1][r][k] * Wc3[k];
        out[(size_t)(r0 + r) * 17 + 16] = acc;
    }
}

extern "C" void kernel_launch(void* const* d_in, const int* in_sizes, int n_in,
                              void* d_out, int out_size, void* d_ws, size_t ws_size,
                              hipStream_t stream) {
    (void)in_sizes; (void)n_in; (void)d_ws; (void)ws_size; (void)out_size;
    const float* hin = (const float*)d_in[0];
    const float* Wx  = (const float*)d_in[1];
    const float* Wh  = (const float*)d_in[2];
    const float* bh  = (const float*)d_in[3];
    const float* Wa1 = (const float*)d_in[4];
    const float* ba1 = (const float*)d_in[5];
    const float* Wa2 = (const float*)d_in[6];
    const float* ba2 = (const float*)d_in[7];
    const float* Wa3 = (const float*)d_in[8];
    const float* ba3 = (const float*)d_in[9];
    const float* ls  = (const float*)d_in[10];
    const float* Wc1 = (const float*)d_in[11];
    const float* bc1 = (const float*)d_in[12];
    const float* Wc2 = (const float*)d_in[13];
    const float* bc2 = (const float*)d_in[14];
    const float* Wc3 = (const float*)d_in[15];
    const float* bc3 = (const float*)d_in[16];

    hipLaunchKernelGGL(ac_fused, dim3(64), dim3(512), 0, stream,
                       hin, Wx, Wh, bh, Wa1, ba1, Wa2, ba2, Wa3, ba3, ls,
                       Wc1, bc1, Wc2, bc2, Wc3, bc3, (float*)d_out);
}